// Round 9
// baseline (90.528 us; speedup 1.0000x reference)
//
#include <hip/hip_runtime.h>

// R8 = R7 resubmission: R7 died to a process-level SIGABRT with no HIP/absmax
// evidence; full OOB audit of all address expressions came up clean. Testing
// the infra-flake hypothesis before bisecting.

#define NUM_BINS 64
#define NPIX (256 * 256)
#define NIMG 16
#define HIST_SIZE (NUM_BINS * NUM_BINS)
#define OUT_ELEMS (NIMG * HIST_SIZE)

#define MM_BLOCKS 256
#define MM_THREADS 256

#define SUBS 64                      // hist blocks per image (exact: 64*1024 = 65536)
#define H_BLOCKS (NIMG * SUBS)       // 1024
#define H_THREADS 256                // 4 waves
#define PPB (NPIX / SUBS)            // 1024 px per block
#define PPW (PPB / 4)                // 256 px per wave
#define STEPS (PPW / 32)             // 8 k-steps of 32 px

#define TROWS 68                     // 64 bins + phantom borders (never read as bins)
#define TCOLS 40                     // K=32 + 8 pad; 80B row stride, 16B-aligned b128
#define TSIZE (TROWS * TCOLS)        // ushorts per matrix tile
#define WREG (2 * TSIZE)             // ushorts per wave region (A + B)

typedef __attribute__((ext_vector_type(8))) short bf16x8;
typedef __attribute__((ext_vector_type(4))) float f32x4;

__device__ __forceinline__ unsigned short f2bf(float f) {
    unsigned int u = __float_as_uint(f);
    unsigned int r = (u + 0x7FFFu + ((u >> 16) & 1u)) >> 16;  // RNE
    return (unsigned short)r;
}

// ================= K1: per-block min/max partials =================
__global__ __launch_bounds__(MM_THREADS) void minmax_part(
        const float4* __restrict__ ref4, const float4* __restrict__ tar4,
        float4* __restrict__ mmpart) {
    const int tid = blockIdx.x * MM_THREADS + threadIdx.x;
    const int stride = MM_BLOCKS * MM_THREADS;
    const int n4 = (NIMG * NPIX) / 4;
    float mnr = 3.0e38f, mxr = -3.0e38f, mnt = 3.0e38f, mxt = -3.0e38f;
    for (int i = tid; i < n4; i += stride) {
        float4 a = ref4[i];
        float4 b = tar4[i];
        mnr = fminf(mnr, fminf(fminf(a.x, a.y), fminf(a.z, a.w)));
        mxr = fmaxf(mxr, fmaxf(fmaxf(a.x, a.y), fmaxf(a.z, a.w)));
        mnt = fminf(mnt, fminf(fminf(b.x, b.y), fminf(b.z, b.w)));
        mxt = fmaxf(mxt, fmaxf(fmaxf(b.x, b.y), fmaxf(b.z, b.w)));
    }
    #pragma unroll
    for (int off = 32; off > 0; off >>= 1) {
        mnr = fminf(mnr, __shfl_down(mnr, off));
        mxr = fmaxf(mxr, __shfl_down(mxr, off));
        mnt = fminf(mnt, __shfl_down(mnt, off));
        mxt = fmaxf(mxt, __shfl_down(mxt, off));
    }
    __shared__ float s[4][MM_THREADS / 64];
    const int wave = threadIdx.x >> 6;
    if ((threadIdx.x & 63) == 0) {
        s[0][wave] = mnr; s[1][wave] = mxr; s[2][wave] = mnt; s[3][wave] = mxt;
    }
    __syncthreads();
    if (threadIdx.x == 0) {
        float a0 = s[0][0], a1 = s[1][0], a2 = s[2][0], a3 = s[3][0];
        #pragma unroll
        for (int w = 1; w < MM_THREADS / 64; ++w) {
            a0 = fminf(a0, s[0][w]);
            a1 = fmaxf(a1, s[1][w]);
            a2 = fminf(a2, s[2][w]);
            a3 = fmaxf(a3, s[3][w]);
        }
        mmpart[blockIdx.x] = make_float4(a0, a1, a2, a3);
    }
}

// ================= K2: MFMA joint histogram ==========================
// Inner loop byte-identical to the R3-proven kernel. Changes vs R3:
// SUBS 32->64 (more blocks, fewer steps) and cbuf 64x65 -> 32x65 with a
// two-row-half epilogue, shrinking LDS 60.2->51.9 KB for 3 blocks/CU.
__global__ __launch_bounds__(H_THREADS) void hist_gemm(
        const float* __restrict__ ref, const float* __restrict__ tar,
        const float4* __restrict__ mmpart, float* __restrict__ part) {
    __shared__ unsigned short tiles[4 * WREG];     // 43520 B
    __shared__ float cbuf[32 * 65];                // 8320 B (stride 65)
    __shared__ float4 smm[4];

    const int tid = threadIdx.x;
    const int wave = tid >> 6;
    const int lane = tid & 63;

    // ---- re-reduce the 256 min/max partials (one per thread) ----
    float4 v = mmpart[tid];
    #pragma unroll
    for (int off = 32; off > 0; off >>= 1) {
        v.x = fminf(v.x, __shfl_down(v.x, off));
        v.y = fmaxf(v.y, __shfl_down(v.y, off));
        v.z = fminf(v.z, __shfl_down(v.z, off));
        v.w = fmaxf(v.w, __shfl_down(v.w, off));
    }
    if (lane == 0) smm[wave] = v;

    // ---- zero this wave's tiles (per-wave private: no barrier needed) ----
    unsigned short* wbase = tiles + wave * WREG;
    {
        uint4 z = {0u, 0u, 0u, 0u};
        uint4* p = (uint4*)wbase;
        #pragma unroll
        for (int i = 0; i < (WREG / 8 + 63) / 64; ++i) {
            int idx = lane + i * 64;
            if (idx < WREG / 8) p[idx] = z;
        }
    }
    __syncthreads();  // smm ready

    const float mn_r = fminf(fminf(smm[0].x, smm[1].x), fminf(smm[2].x, smm[3].x));
    const float mx_r = fmaxf(fmaxf(smm[0].y, smm[1].y), fmaxf(smm[2].y, smm[3].y));
    const float mn_t = fminf(fminf(smm[0].z, smm[1].z), fminf(smm[2].z, smm[3].z));
    const float mx_t = fmaxf(fmaxf(smm[0].w, smm[1].w), fmaxf(smm[2].w, smm[3].w));

    const bool isRef = (lane < 32);
    const float mn = isRef ? mn_r : mn_t;
    const float sc = isRef ? (64.0f / (mx_r - mn_r)) : (64.0f / (mx_t - mn_t));
    const float* __restrict__ src = isRef ? ref : tar;
    unsigned short* T = wbase + (isRef ? 0 : TSIZE);
    const int col = lane & 31;

    const int img = blockIdx.x / SUBS;
    const int sub = blockIdx.x % SUBS;
    const int pbase = img * NPIX + sub * PPB + wave * PPW + col;

    f32x4 acc[4][4];
    #pragma unroll
    for (int a = 0; a < 4; ++a)
        #pragma unroll
        for (int b = 0; b < 4; ++b)
            acc[a][b] = (f32x4){0.f, 0.f, 0.f, 0.f};

    const unsigned short* aT = wbase;
    const unsigned short* bT = wbase + TSIZE;
    const int frow = (lane & 15) + 1;   // bin m -> physical row m+1
    const int fk = (lane >> 4) * 8;     // k slice within K=32

    int prev = 0;
    float vcur = src[pbase];
    for (int s = 0; s < STEPS; ++s) {
        float vnext = (s + 1 < STEPS) ? src[pbase + (s + 1) * 32] : 0.0f;
        float x = (vcur - mn) * sc;              // in [0, 64]
        float fx = floorf(x);
        int ib = (int)fx;                        // physical first row (= ir+1), 0..64
        float u = x - fx;
        float um = 1.0f - u;
        float w0 = um * um * um * (1.0f / 6.0f);
        float w1 = (2.0f / 3.0f) - u * u + 0.5f * u * u * u;
        float w2 = (2.0f / 3.0f) - um * um + 0.5f * um * um * um;
        float w3 = u * u * u * (1.0f / 6.0f);
        unsigned short h0 = f2bf(w0), h1 = f2bf(w1), h2 = f2bf(w2), h3 = f2bf(w3);

        // un-zero previous step's 4 cells, then scatter the new 4 (DS in-order per wave)
        unsigned short* tp = T + prev * TCOLS + col;
        tp[0] = 0; tp[TCOLS] = 0; tp[2 * TCOLS] = 0; tp[3 * TCOLS] = 0;
        unsigned short* tn = T + ib * TCOLS + col;
        tn[0] = h0; tn[TCOLS] = h1; tn[2 * TCOLS] = h2; tn[3 * TCOLS] = h3;
        prev = ib;

        bf16x8 af[4], bfr[4];
        #pragma unroll
        for (int mt = 0; mt < 4; ++mt)
            af[mt] = *(const bf16x8*)(aT + (mt * 16 + frow) * TCOLS + fk);
        #pragma unroll
        for (int nt = 0; nt < 4; ++nt)
            bfr[nt] = *(const bf16x8*)(bT + (nt * 16 + frow) * TCOLS + fk);
        #pragma unroll
        for (int mt = 0; mt < 4; ++mt)
            #pragma unroll
            for (int nt = 0; nt < 4; ++nt)
                acc[mt][nt] = __builtin_amdgcn_mfma_f32_16x16x32_bf16(
                    af[mt], bfr[nt], acc[mt][nt], 0, 0, 0);
        vcur = vnext;
    }

    // ---- combine waves' C in two row-halves (cbuf holds 32 rows) ----
    // C/D layout: col=lane&15, row=quad*4+reg (verified m89/m91)
    const int crow0 = (lane >> 4) * 4;
    const int ccol = lane & 15;
    float* po = part + (size_t)blockIdx.x * HIST_SIZE;
    for (int half = 0; half < 2; ++half) {
        for (int ph = 0; ph < 4; ++ph) {
            if (wave == ph) {
                #pragma unroll
                for (int mh = 0; mh < 2; ++mh) {
                    int mt = half * 2 + mh;
                    #pragma unroll
                    for (int nt = 0; nt < 4; ++nt)
                        #pragma unroll
                        for (int r = 0; r < 4; ++r) {
                            int idx = (mh * 16 + crow0 + r) * 65 + nt * 16 + ccol;
                            if (ph == 0) cbuf[idx] = acc[mt][nt][r];
                            else cbuf[idx] += acc[mt][nt][r];
                        }
                }
            }
            __syncthreads();
        }
        // flush this half's 32 rows (2048 floats)
        for (int c = tid; c < HIST_SIZE / 2; c += H_THREADS)
            po[half * (HIST_SIZE / 2) + c] = cbuf[(c >> 6) * 65 + (c & 63)];
        __syncthreads();   // cbuf reads done before next half overwrites
    }
}

// ================= K3: reduce SUBS partials per image, scale, store ============
__global__ __launch_bounds__(256) void reduce_k(
        const float* __restrict__ part, float* __restrict__ out) {
    const int i = blockIdx.x * 256 + threadIdx.x;
    const int img = i >> 12;
    const int c = i & (HIST_SIZE - 1);
    const float* p = part + (size_t)(img * SUBS) * HIST_SIZE + c;
    float sum = 0.0f;
    #pragma unroll 8
    for (int s = 0; s < SUBS; ++s) sum += p[(size_t)s * HIST_SIZE];
    out[i] = sum * 4096.0f;  // 1/EPS^2
}

extern "C" void kernel_launch(void* const* d_in, const int* in_sizes, int n_in,
                              void* d_out, int out_size, void* d_ws, size_t ws_size,
                              hipStream_t stream) {
    const float* ref = (const float*)d_in[0];
    const float* tar = (const float*)d_in[1];
    float* out = (float*)d_out;

    float4* mmpart = (float4*)d_ws;
    float* part = (float*)((char*)d_ws + MM_BLOCKS * sizeof(float4));

    minmax_part<<<MM_BLOCKS, MM_THREADS, 0, stream>>>(
        (const float4*)ref, (const float4*)tar, mmpart);
    hist_gemm<<<H_BLOCKS, H_THREADS, 0, stream>>>(ref, tar, mmpart, part);
    reduce_k<<<OUT_ELEMS / 256, 256, 0, stream>>>(part, out);
}

// Round 10
// 90.276 us; speedup vs baseline: 1.0028x; 1.0028x over previous
//
#include <hip/hip_runtime.h>

#define NUM_BINS 64
#define NPIX (256 * 256)
#define NIMG 16
#define HIST_SIZE (NUM_BINS * NUM_BINS)
#define OUT_ELEMS (NIMG * HIST_SIZE)

#define MM_BLOCKS 256
#define MM_THREADS 256

#define SUBS 48                      // 768 blocks = 256 CU x 3 resident: one clean round
#define H_BLOCKS (NIMG * SUBS)       // 768
#define H_THREADS 128                // 2 waves
#define PPW 704                      // 22 steps x 32 px
#define PPB (2 * PPW)                // 1408 slots/block (ragged: 48*1408=67584, tail masked)
#define STEPS (PPW / 32)             // 22 (even: unroll-2 folds buffer indices)

#define TROWS 68                     // rows: bins -1..66 (phantom borders, never read)
#define TCOLS 40                     // K=32 + 8 pad; 80B stride -> exact 2-way (free) on b128
#define TSIZE (TROWS * TCOLS)        // 2720 ushorts per operand tile
#define WBUF (2 * TSIZE)             // one buffer slot: A+B = 5440 ushorts
#define WREGW (2 * WBUF)             // per-wave: buf0+buf1 = 10880 ushorts (21760 B)

typedef __attribute__((ext_vector_type(8))) short bf16x8;
typedef __attribute__((ext_vector_type(4))) float f32x4;

__device__ __forceinline__ unsigned short f2bf(float f) {
    unsigned int u = __float_as_uint(f);
    unsigned int r = (u + 0x7FFFu + ((u >> 16) & 1u)) >> 16;  // RNE
    return (unsigned short)r;
}

// ================= K1: per-block min/max partials =================
__global__ __launch_bounds__(MM_THREADS) void minmax_part(
        const float4* __restrict__ ref4, const float4* __restrict__ tar4,
        float4* __restrict__ mmpart) {
    const int tid = blockIdx.x * MM_THREADS + threadIdx.x;
    const int stride = MM_BLOCKS * MM_THREADS;
    const int n4 = (NIMG * NPIX) / 4;
    float mnr = 3.0e38f, mxr = -3.0e38f, mnt = 3.0e38f, mxt = -3.0e38f;
    for (int i = tid; i < n4; i += stride) {
        float4 a = ref4[i];
        float4 b = tar4[i];
        mnr = fminf(mnr, fminf(fminf(a.x, a.y), fminf(a.z, a.w)));
        mxr = fmaxf(mxr, fmaxf(fmaxf(a.x, a.y), fmaxf(a.z, a.w)));
        mnt = fminf(mnt, fminf(fminf(b.x, b.y), fminf(b.z, b.w)));
        mxt = fmaxf(mxt, fmaxf(fmaxf(b.x, b.y), fmaxf(b.z, b.w)));
    }
    #pragma unroll
    for (int off = 32; off > 0; off >>= 1) {
        mnr = fminf(mnr, __shfl_down(mnr, off));
        mxr = fmaxf(mxr, __shfl_down(mxr, off));
        mnt = fminf(mnt, __shfl_down(mnt, off));
        mxt = fmaxf(mxt, __shfl_down(mxt, off));
    }
    __shared__ float s[4][MM_THREADS / 64];
    const int wave = threadIdx.x >> 6;
    if ((threadIdx.x & 63) == 0) {
        s[0][wave] = mnr; s[1][wave] = mxr; s[2][wave] = mnt; s[3][wave] = mxt;
    }
    __syncthreads();
    if (threadIdx.x == 0) {
        float a0 = s[0][0], a1 = s[1][0], a2 = s[2][0], a3 = s[3][0];
        #pragma unroll
        for (int w = 1; w < MM_THREADS / 64; ++w) {
            a0 = fminf(a0, s[0][w]);
            a1 = fmaxf(a1, s[1][w]);
            a2 = fminf(a2, s[2][w]);
            a3 = fmaxf(a3, s[3][w]);
        }
        mmpart[blockIdx.x] = make_float4(a0, a1, a2, a3);
    }
}

// ================= K2: MFMA joint histogram, double-buffered tiles ============
// Step s: read fragments from buf[s&1] (written one iteration ago -> latency
// hidden), write step s+1 into buf[(s+1)&1]. In-order per-wave DS guarantees
// reads(s-1) of buf[b] complete before writes(s+1) overwrite buf[b]: race-free.
__global__ __launch_bounds__(H_THREADS) void hist_gemm(
        const float* __restrict__ ref, const float* __restrict__ tar,
        const float4* __restrict__ mmpart, float* __restrict__ part) {
    __shared__ __align__(16) unsigned short tiles[2 * WREGW];  // 43520 B
    __shared__ float cbuf[32 * 65];                            // 8320 B
    __shared__ float4 smm[2];
    // total 51.9 KB -> 3 blocks/CU

    const int tid = threadIdx.x;
    const int wave = tid >> 6;
    const int lane = tid & 63;

    // ---- re-reduce the 256 min/max partials (two per thread) ----
    float4 va = mmpart[tid];
    float4 vb = mmpart[tid + 128];
    float4 v = make_float4(fminf(va.x, vb.x), fmaxf(va.y, vb.y),
                           fminf(va.z, vb.z), fmaxf(va.w, vb.w));
    #pragma unroll
    for (int off = 32; off > 0; off >>= 1) {
        v.x = fminf(v.x, __shfl_down(v.x, off));
        v.y = fmaxf(v.y, __shfl_down(v.y, off));
        v.z = fminf(v.z, __shfl_down(v.z, off));
        v.w = fmaxf(v.w, __shfl_down(v.w, off));
    }
    if (lane == 0) smm[wave] = v;

    // ---- zero this wave's buffers (per-wave private) ----
    unsigned short* wbase = tiles + wave * WREGW;
    {
        uint4 z = {0u, 0u, 0u, 0u};
        uint4* p = (uint4*)wbase;
        #pragma unroll
        for (int i = 0; i < (WREGW / 8 + 63) / 64; ++i) {
            int idx = lane + i * 64;
            if (idx < WREGW / 8) p[idx] = z;
        }
    }
    __syncthreads();  // smm ready

    const float mn_r = fminf(smm[0].x, smm[1].x);
    const float mx_r = fmaxf(smm[0].y, smm[1].y);
    const float mn_t = fminf(smm[0].z, smm[1].z);
    const float mx_t = fmaxf(smm[0].w, smm[1].w);

    const bool isRef = (lane < 32);
    const float mn = isRef ? mn_r : mn_t;
    const float sc = isRef ? (64.0f / (mx_r - mn_r)) : (64.0f / (mx_t - mn_t));
    const float* __restrict__ src = isRef ? ref : tar;
    unsigned short* Tbase = wbase + (isRef ? 0 : TSIZE);  // my tile in buf0
    const int col = lane & 31;

    const int img = blockIdx.x / SUBS;
    const int sub = blockIdx.x % SUBS;
    const int poff0 = sub * PPB + wave * PPW + col;   // in-image offset (may exceed NPIX)
    const int ibase = img * NPIX;

    f32x4 acc[4][4];
    #pragma unroll
    for (int a = 0; a < 4; ++a)
        #pragma unroll
        for (int b = 0; b < 4; ++b)
            acc[a][b] = (f32x4){0.f, 0.f, 0.f, 0.f};

    const int frow = (lane & 15) + 1;   // bin m -> physical row m+1
    const int fk = (lane >> 4) * 8;     // k slice within K=32

    int prev[2];
    float vnext;
    {   // ---- prologue: step-0 weights into buf0; fetch step-1 value ----
        float v0 = src[ibase + (poff0 < NPIX ? poff0 : 0)];
        float x = (v0 - mn) * sc;
        float fx = floorf(x);
        int ib = (int)fx;
        float u = x - fx, um = 1.0f - u;
        unsigned short h0 = f2bf(um * um * um * (1.0f / 6.0f));
        unsigned short h1 = f2bf((2.0f / 3.0f) - u * u + 0.5f * u * u * u);
        unsigned short h2 = f2bf((2.0f / 3.0f) - um * um + 0.5f * um * um * um);
        unsigned short h3 = f2bf(u * u * u * (1.0f / 6.0f));
        if (poff0 >= NPIX) { h0 = 0; h1 = 0; h2 = 0; h3 = 0; }
        unsigned short* tn = Tbase + ib * TCOLS + col;
        tn[0] = h0; tn[TCOLS] = h1; tn[2 * TCOLS] = h2; tn[3 * TCOLS] = h3;
        prev[0] = ib;
        prev[1] = 0;                 // buf1 rows 0..3 are zero: first un-zero harmless
        int off1 = poff0 + 32;
        vnext = src[ibase + (off1 < NPIX ? off1 : 0)];
    }

    #pragma unroll 2                 // folds cur/nxt & prev[] indices to constants
    for (int s = 0; s < STEPS; ++s) {
        const int cur = s & 1, nxt = cur ^ 1;
        // 1) fragment reads from buf[cur] (its writes issued one iteration ago)
        const unsigned short* aT = wbase + cur * WBUF;
        const unsigned short* bT = aT + TSIZE;
        bf16x8 af[4], bfr[4];
        #pragma unroll
        for (int mt = 0; mt < 4; ++mt)
            af[mt] = *(const bf16x8*)(aT + (mt * 16 + frow) * TCOLS + fk);
        #pragma unroll
        for (int nt = 0; nt < 4; ++nt)
            bfr[nt] = *(const bf16x8*)(bT + (nt * 16 + frow) * TCOLS + fk);

        // 2) weights for step s+1 (dead write when s+1==STEPS: never read)
        float x = (vnext - mn) * sc;
        float fx = floorf(x);
        int ib = (int)fx;
        float u = x - fx, um = 1.0f - u;
        unsigned short h0 = f2bf(um * um * um * (1.0f / 6.0f));
        unsigned short h1 = f2bf((2.0f / 3.0f) - u * u + 0.5f * u * u * u);
        unsigned short h2 = f2bf((2.0f / 3.0f) - um * um + 0.5f * um * um * um);
        unsigned short h3 = f2bf(u * u * u * (1.0f / 6.0f));
        if (poff0 + (s + 1) * 32 >= NPIX) { h0 = 0; h1 = 0; h2 = 0; h3 = 0; }

        // 3) prefetch step s+2's value
        int offn = poff0 + (s + 2) * 32;
        float vpre = src[ibase + ((s + 2 < STEPS && offn < NPIX) ? offn : 0)];

        // 4) un-zero buf[nxt]'s stale rows (from step s-1), write step s+1
        unsigned short* Tn = Tbase + nxt * WBUF;
        unsigned short* tp = Tn + prev[nxt] * TCOLS + col;
        tp[0] = 0; tp[TCOLS] = 0; tp[2 * TCOLS] = 0; tp[3 * TCOLS] = 0;
        unsigned short* tw = Tn + ib * TCOLS + col;
        tw[0] = h0; tw[TCOLS] = h1; tw[2 * TCOLS] = h2; tw[3 * TCOLS] = h3;
        prev[nxt] = ib;

        // 5) MFMA on step s's fragments
        #pragma unroll
        for (int mt = 0; mt < 4; ++mt)
            #pragma unroll
            for (int nt = 0; nt < 4; ++nt)
                acc[mt][nt] = __builtin_amdgcn_mfma_f32_16x16x32_bf16(
                    af[mt], bfr[nt], acc[mt][nt], 0, 0, 0);
        vnext = vpre;
    }

    // ---- combine 2 waves' C in two row-halves (cbuf holds 32 rows) ----
    const int crow0 = (lane >> 4) * 4;
    const int ccol = lane & 15;
    float* po = part + (size_t)blockIdx.x * HIST_SIZE;
    for (int half = 0; half < 2; ++half) {
        for (int ph = 0; ph < 2; ++ph) {
            if (wave == ph) {
                #pragma unroll
                for (int mh = 0; mh < 2; ++mh) {
                    int mt = half * 2 + mh;
                    #pragma unroll
                    for (int nt = 0; nt < 4; ++nt)
                        #pragma unroll
                        for (int r = 0; r < 4; ++r) {
                            int idx = (mh * 16 + crow0 + r) * 65 + nt * 16 + ccol;
                            if (ph == 0) cbuf[idx] = acc[mt][nt][r];
                            else cbuf[idx] += acc[mt][nt][r];
                        }
                }
            }
            __syncthreads();
        }
        for (int c = tid; c < HIST_SIZE / 2; c += H_THREADS)
            po[half * (HIST_SIZE / 2) + c] = cbuf[(c >> 6) * 65 + (c & 63)];
        __syncthreads();   // cbuf reads done before next half overwrites
    }
}

// ================= K3: reduce SUBS partials per image, scale, store ============
__global__ __launch_bounds__(256) void reduce_k(
        const float* __restrict__ part, float* __restrict__ out) {
    const int i = blockIdx.x * 256 + threadIdx.x;
    const int img = i >> 12;
    const int c = i & (HIST_SIZE - 1);
    const float* p = part + (size_t)(img * SUBS) * HIST_SIZE + c;
    float sum = 0.0f;
    #pragma unroll 8
    for (int s = 0; s < SUBS; ++s) sum += p[(size_t)s * HIST_SIZE];
    out[i] = sum * 4096.0f;  // 1/EPS^2
}

extern "C" void kernel_launch(void* const* d_in, const int* in_sizes, int n_in,
                              void* d_out, int out_size, void* d_ws, size_t ws_size,
                              hipStream_t stream) {
    const float* ref = (const float*)d_in[0];
    const float* tar = (const float*)d_in[1];
    float* out = (float*)d_out;

    float4* mmpart = (float4*)d_ws;
    float* part = (float*)((char*)d_ws + MM_BLOCKS * sizeof(float4));

    minmax_part<<<MM_BLOCKS, MM_THREADS, 0, stream>>>(
        (const float4*)ref, (const float4*)tar, mmpart);
    hist_gemm<<<H_BLOCKS, H_THREADS, 0, stream>>>(ref, tar, mmpart, part);
    reduce_k<<<OUT_ELEMS / 256, 256, 0, stream>>>(part, out);
}

// Round 11
// 87.270 us; speedup vs baseline: 1.0373x; 1.0344x over previous
//
#include <hip/hip_runtime.h>

#define NUM_BINS 64
#define NPIX (256 * 256)
#define NIMG 16
#define HIST_SIZE (NUM_BINS * NUM_BINS)
#define OUT_ELEMS (NIMG * HIST_SIZE)

#define MM_BLOCKS 256
#define MM_THREADS 256

#define SUBS 32                      // hist blocks per image (exact division)
#define H_BLOCKS (NIMG * SUBS)       // 512
#define H_THREADS 256                // 4 waves
#define PPB (NPIX / SUBS)            // 2048 px per block
#define PPW (PPB / 4)                // 512 px per wave
#define STEPS (PPW / 32)             // 16 k-steps of 32 px

// Swizzled pad-free tile: row stride 32 ushorts (64 B). Element (r, c):
//   addr = r*32 + (((c>>3) ^ (r&3)) << 3) + (c&7)
// 16-B chunks hold cols 8k..8k+7 in order (fragment semantics intact); the
// XOR rotates chunk->bank mapping per row, putting b128 fragment reads at the
// 8-access/bank floor (TCOLS=40's 20-word stride clustered rows on 8 bank
// positions -> ~2x read cost; R6 measured 2.3M SQ_LDS_BANK_CONFLICT).
#define TROWS 68                     // rows: bins -1..66 (phantom borders)
#define TK 32                        // ushorts per row
#define TSIZE (TROWS * TK)           // 2176 ushorts per operand tile
#define WREG (2 * TSIZE)             // ushorts per wave region (A + B) = 4352

typedef __attribute__((ext_vector_type(8))) short bf16x8;
typedef __attribute__((ext_vector_type(4))) float f32x4;

__device__ __forceinline__ int taddr(int r, int c) {
    return (r << 5) + ((((c >> 3) ^ r) & 3) << 3) + (c & 7);
}

__device__ __forceinline__ unsigned short f2bf(float f) {
    unsigned int u = __float_as_uint(f);
    unsigned int r = (u + 0x7FFFu + ((u >> 16) & 1u)) >> 16;  // RNE
    return (unsigned short)r;
}

// ================= K1: per-block min/max partials =================
__global__ __launch_bounds__(MM_THREADS) void minmax_part(
        const float4* __restrict__ ref4, const float4* __restrict__ tar4,
        float4* __restrict__ mmpart) {
    const int tid = blockIdx.x * MM_THREADS + threadIdx.x;
    const int stride = MM_BLOCKS * MM_THREADS;
    const int n4 = (NIMG * NPIX) / 4;
    float mnr = 3.0e38f, mxr = -3.0e38f, mnt = 3.0e38f, mxt = -3.0e38f;
    for (int i = tid; i < n4; i += stride) {
        float4 a = ref4[i];
        float4 b = tar4[i];
        mnr = fminf(mnr, fminf(fminf(a.x, a.y), fminf(a.z, a.w)));
        mxr = fmaxf(mxr, fmaxf(fmaxf(a.x, a.y), fmaxf(a.z, a.w)));
        mnt = fminf(mnt, fminf(fminf(b.x, b.y), fminf(b.z, b.w)));
        mxt = fmaxf(mxt, fmaxf(fmaxf(b.x, b.y), fmaxf(b.z, b.w)));
    }
    #pragma unroll
    for (int off = 32; off > 0; off >>= 1) {
        mnr = fminf(mnr, __shfl_down(mnr, off));
        mxr = fmaxf(mxr, __shfl_down(mxr, off));
        mnt = fminf(mnt, __shfl_down(mnt, off));
        mxt = fmaxf(mxt, __shfl_down(mxt, off));
    }
    __shared__ float s[4][MM_THREADS / 64];
    const int wave = threadIdx.x >> 6;
    if ((threadIdx.x & 63) == 0) {
        s[0][wave] = mnr; s[1][wave] = mxr; s[2][wave] = mnt; s[3][wave] = mxt;
    }
    __syncthreads();
    if (threadIdx.x == 0) {
        float a0 = s[0][0], a1 = s[1][0], a2 = s[2][0], a3 = s[3][0];
        #pragma unroll
        for (int w = 1; w < MM_THREADS / 64; ++w) {
            a0 = fminf(a0, s[0][w]);
            a1 = fmaxf(a1, s[1][w]);
            a2 = fminf(a2, s[2][w]);
            a3 = fmaxf(a3, s[3][w]);
        }
        mmpart[blockIdx.x] = make_float4(a0, a1, a2, a3);
    }
}

// ================= K2: MFMA joint histogram (swizzled tiles) ==================
// Schedule and op ordering byte-identical to the R6-proven kernel; only the
// tile address mapping changed (taddr swizzle, pad-free 64B rows).
__global__ __launch_bounds__(H_THREADS) void hist_gemm(
        const float* __restrict__ ref, const float* __restrict__ tar,
        const float4* __restrict__ mmpart, float* __restrict__ part) {
    __shared__ __align__(16) unsigned short tiles[4 * WREG];   // 34816 B
    __shared__ float cbuf[64 * 65];                            // 16640 B
    __shared__ float4 smm[4];
    // total 51.5 KB

    const int tid = threadIdx.x;
    const int wave = tid >> 6;
    const int lane = tid & 63;

    // ---- re-reduce the 256 min/max partials (one per thread) ----
    float4 v = mmpart[tid];
    #pragma unroll
    for (int off = 32; off > 0; off >>= 1) {
        v.x = fminf(v.x, __shfl_down(v.x, off));
        v.y = fmaxf(v.y, __shfl_down(v.y, off));
        v.z = fminf(v.z, __shfl_down(v.z, off));
        v.w = fmaxf(v.w, __shfl_down(v.w, off));
    }
    if (lane == 0) smm[wave] = v;

    // ---- zero this wave's tiles (per-wave private: no barrier needed) ----
    unsigned short* wbase = tiles + wave * WREG;
    {
        uint4 z = {0u, 0u, 0u, 0u};
        uint4* p = (uint4*)wbase;
        #pragma unroll
        for (int i = 0; i < (WREG / 8 + 63) / 64; ++i) {
            int idx = lane + i * 64;
            if (idx < WREG / 8) p[idx] = z;
        }
    }
    __syncthreads();  // smm ready

    const float mn_r = fminf(fminf(smm[0].x, smm[1].x), fminf(smm[2].x, smm[3].x));
    const float mx_r = fmaxf(fmaxf(smm[0].y, smm[1].y), fmaxf(smm[2].y, smm[3].y));
    const float mn_t = fminf(fminf(smm[0].z, smm[1].z), fminf(smm[2].z, smm[3].z));
    const float mx_t = fmaxf(fmaxf(smm[0].w, smm[1].w), fmaxf(smm[2].w, smm[3].w));

    const bool isRef = (lane < 32);
    const float mn = isRef ? mn_r : mn_t;
    const float sc = isRef ? (64.0f / (mx_r - mn_r)) : (64.0f / (mx_t - mn_t));
    const float* __restrict__ src = isRef ? ref : tar;
    unsigned short* T = wbase + (isRef ? 0 : TSIZE);
    const int col = lane & 31;

    const int img = blockIdx.x / SUBS;
    const int sub = blockIdx.x % SUBS;
    const int pbase = img * NPIX + sub * PPB + wave * PPW + col;

    f32x4 acc[4][4];
    #pragma unroll
    for (int a = 0; a < 4; ++a)
        #pragma unroll
        for (int b = 0; b < 4; ++b)
            acc[a][b] = (f32x4){0.f, 0.f, 0.f, 0.f};

    const unsigned short* aT = wbase;
    const unsigned short* bT = wbase + TSIZE;
    const int frow = (lane & 15) + 1;           // bin m -> physical row m+1
    const int kc = lane >> 4;                    // k-chunk 0..3 (8 ushorts each)
    const int choff = ((kc ^ (frow & 3)) << 3);  // swizzled chunk offset (mt*16 preserves r&3)

    int prev = 0;
    float vcur = src[pbase];
    for (int s = 0; s < STEPS; ++s) {
        float vnext = (s + 1 < STEPS) ? src[pbase + (s + 1) * 32] : 0.0f;
        float x = (vcur - mn) * sc;              // in [0, 64]
        float fx = floorf(x);
        int ib = (int)fx;                        // physical first row (= ir+1), 0..64
        float u = x - fx;
        float um = 1.0f - u;
        float w0 = um * um * um * (1.0f / 6.0f);
        float w1 = (2.0f / 3.0f) - u * u + 0.5f * u * u * u;
        float w2 = (2.0f / 3.0f) - um * um + 0.5f * um * um * um;
        float w3 = u * u * u * (1.0f / 6.0f);
        unsigned short h0 = f2bf(w0), h1 = f2bf(w1), h2 = f2bf(w2), h3 = f2bf(w3);

        // un-zero previous step's 4 cells, then scatter the new 4 (DS in-order per wave)
        T[taddr(prev, col)] = 0;
        T[taddr(prev + 1, col)] = 0;
        T[taddr(prev + 2, col)] = 0;
        T[taddr(prev + 3, col)] = 0;
        T[taddr(ib, col)] = h0;
        T[taddr(ib + 1, col)] = h1;
        T[taddr(ib + 2, col)] = h2;
        T[taddr(ib + 3, col)] = h3;
        prev = ib;

        bf16x8 af[4], bfr[4];
        #pragma unroll
        for (int mt = 0; mt < 4; ++mt)
            af[mt] = *(const bf16x8*)(aT + ((mt * 16 + frow) << 5) + choff);
        #pragma unroll
        for (int nt = 0; nt < 4; ++nt)
            bfr[nt] = *(const bf16x8*)(bT + ((nt * 16 + frow) << 5) + choff);
        #pragma unroll
        for (int mt = 0; mt < 4; ++mt)
            #pragma unroll
            for (int nt = 0; nt < 4; ++nt)
                acc[mt][nt] = __builtin_amdgcn_mfma_f32_16x16x32_bf16(
                    af[mt], bfr[nt], acc[mt][nt], 0, 0, 0);
        vcur = vnext;
    }

    // ---- combine the 4 waves' C into cbuf (C/D: col=lane&15, row=quad*4+reg) ----
    const int crow0 = (lane >> 4) * 4;
    const int ccol = lane & 15;
    for (int ph = 0; ph < 4; ++ph) {
        if (wave == ph) {
            #pragma unroll
            for (int mt = 0; mt < 4; ++mt)
                #pragma unroll
                for (int nt = 0; nt < 4; ++nt)
                    #pragma unroll
                    for (int r = 0; r < 4; ++r) {
                        int idx = (mt * 16 + crow0 + r) * 65 + nt * 16 + ccol;
                        if (ph == 0) cbuf[idx] = acc[mt][nt][r];
                        else cbuf[idx] += acc[mt][nt][r];
                    }
        }
        __syncthreads();
    }
    float* po = part + (size_t)blockIdx.x * HIST_SIZE;
    for (int c = tid; c < HIST_SIZE; c += H_THREADS)
        po[c] = cbuf[(c >> 6) * 65 + (c & 63)];
}

// ================= K3: reduce SUBS partials per image, scale, store ============
__global__ __launch_bounds__(256) void reduce_k(
        const float* __restrict__ part, float* __restrict__ out) {
    const int i = blockIdx.x * 256 + threadIdx.x;
    const int img = i >> 12;
    const int c = i & (HIST_SIZE - 1);
    const float* p = part + (size_t)(img * SUBS) * HIST_SIZE + c;
    float sum = 0.0f;
    #pragma unroll
    for (int s = 0; s < SUBS; ++s) sum += p[(size_t)s * HIST_SIZE];
    out[i] = sum * 4096.0f;  // 1/EPS^2
}

extern "C" void kernel_launch(void* const* d_in, const int* in_sizes, int n_in,
                              void* d_out, int out_size, void* d_ws, size_t ws_size,
                              hipStream_t stream) {
    const float* ref = (const float*)d_in[0];
    const float* tar = (const float*)d_in[1];
    float* out = (float*)d_out;

    float4* mmpart = (float4*)d_ws;
    float* part = (float*)((char*)d_ws + MM_BLOCKS * sizeof(float4));

    minmax_part<<<MM_BLOCKS, MM_THREADS, 0, stream>>>(
        (const float4*)ref, (const float4*)tar, mmpart);
    hist_gemm<<<H_BLOCKS, H_THREADS, 0, stream>>>(ref, tar, mmpart, part);
    reduce_k<<<OUT_ELEMS / 256, 256, 0, stream>>>(part, out);
}

// Round 12
// 84.575 us; speedup vs baseline: 1.0704x; 1.0319x over previous
//
#include <hip/hip_runtime.h>

#define NUM_BINS 64
#define NPIX (256 * 256)
#define NIMG 16
#define HIST_SIZE (NUM_BINS * NUM_BINS)
#define OUT_ELEMS (NIMG * HIST_SIZE)

#define MM_BLOCKS 256
#define MM_THREADS 256

#define SUBS 32                      // hist blocks per image (exact division)
#define H_BLOCKS (NIMG * SUBS)       // 512
#define H_THREADS 256                // 4 waves
#define PPB (NPIX / SUBS)            // 2048 px per block
#define PPW (PPB / 4)                // 512 px per wave
#define STEPS (PPW / 32)             // 16 k-steps of 32 px

#define TROWS 68                     // 64 bins + phantom borders (never read as bins)
#define TCOLS 40                     // K=32 + 8 pad; 80B row stride (reads at 8/bank floor)
#define TSIZE (TROWS * TCOLS)        // ushorts per matrix tile
#define WREG (2 * TSIZE)             // ushorts per wave region (A + B)

typedef __attribute__((ext_vector_type(8))) short bf16x8;
typedef __attribute__((ext_vector_type(4))) float f32x4;

__device__ __forceinline__ unsigned short f2bf(float f) {
    unsigned int u = __float_as_uint(f);
    unsigned int r = (u + 0x7FFFu + ((u >> 16) & 1u)) >> 16;  // RNE
    return (unsigned short)r;
}

// ================= K1: per-block min/max partials =================
__global__ __launch_bounds__(MM_THREADS) void minmax_part(
        const float4* __restrict__ ref4, const float4* __restrict__ tar4,
        float4* __restrict__ mmpart) {
    const int tid = blockIdx.x * MM_THREADS + threadIdx.x;
    const int stride = MM_BLOCKS * MM_THREADS;
    const int n4 = (NIMG * NPIX) / 4;
    float mnr = 3.0e38f, mxr = -3.0e38f, mnt = 3.0e38f, mxt = -3.0e38f;
    for (int i = tid; i < n4; i += stride) {
        float4 a = ref4[i];
        float4 b = tar4[i];
        mnr = fminf(mnr, fminf(fminf(a.x, a.y), fminf(a.z, a.w)));
        mxr = fmaxf(mxr, fmaxf(fmaxf(a.x, a.y), fmaxf(a.z, a.w)));
        mnt = fminf(mnt, fminf(fminf(b.x, b.y), fminf(b.z, b.w)));
        mxt = fmaxf(mxt, fmaxf(fmaxf(b.x, b.y), fmaxf(b.z, b.w)));
    }
    #pragma unroll
    for (int off = 32; off > 0; off >>= 1) {
        mnr = fminf(mnr, __shfl_down(mnr, off));
        mxr = fmaxf(mxr, __shfl_down(mxr, off));
        mnt = fminf(mnt, __shfl_down(mnt, off));
        mxt = fmaxf(mxt, __shfl_down(mxt, off));
    }
    __shared__ float s[4][MM_THREADS / 64];
    const int wave = threadIdx.x >> 6;
    if ((threadIdx.x & 63) == 0) {
        s[0][wave] = mnr; s[1][wave] = mxr; s[2][wave] = mnt; s[3][wave] = mxt;
    }
    __syncthreads();
    if (threadIdx.x == 0) {
        float a0 = s[0][0], a1 = s[1][0], a2 = s[2][0], a3 = s[3][0];
        #pragma unroll
        for (int w = 1; w < MM_THREADS / 64; ++w) {
            a0 = fminf(a0, s[0][w]);
            a1 = fmaxf(a1, s[1][w]);
            a2 = fminf(a2, s[2][w]);
            a3 = fmaxf(a3, s[3][w]);
        }
        mmpart[blockIdx.x] = make_float4(a0, a1, a2, a3);
    }
}

// ================= K2: MFMA joint histogram (R6-proven inner loop) ============
// Epilogue fused: block partials go straight to out via atomicAdd (out is
// zeroed by a memset node before this kernel; R1/R2 showed this flush pattern
// is ~free). reduce_k and the 16.8 MB part round-trip are eliminated.
__global__ __launch_bounds__(H_THREADS) void hist_gemm(
        const float* __restrict__ ref, const float* __restrict__ tar,
        const float4* __restrict__ mmpart, float* __restrict__ out) {
    __shared__ unsigned short tiles[4 * WREG];     // 43520 B
    __shared__ float cbuf[64 * 65];                // 16640 B (stride 65)
    __shared__ float4 smm[4];

    const int tid = threadIdx.x;
    const int wave = tid >> 6;
    const int lane = tid & 63;

    // ---- re-reduce the 256 min/max partials (one per thread) ----
    float4 v = mmpart[tid];
    #pragma unroll
    for (int off = 32; off > 0; off >>= 1) {
        v.x = fminf(v.x, __shfl_down(v.x, off));
        v.y = fmaxf(v.y, __shfl_down(v.y, off));
        v.z = fminf(v.z, __shfl_down(v.z, off));
        v.w = fmaxf(v.w, __shfl_down(v.w, off));
    }
    if (lane == 0) smm[wave] = v;

    // ---- zero this wave's tiles (per-wave private: no barrier needed) ----
    unsigned short* wbase = tiles + wave * WREG;
    {
        uint4 z = {0u, 0u, 0u, 0u};
        uint4* p = (uint4*)wbase;
        #pragma unroll
        for (int i = 0; i < (WREG / 8 + 63) / 64; ++i) {
            int idx = lane + i * 64;
            if (idx < WREG / 8) p[idx] = z;
        }
    }
    __syncthreads();  // smm ready

    const float mn_r = fminf(fminf(smm[0].x, smm[1].x), fminf(smm[2].x, smm[3].x));
    const float mx_r = fmaxf(fmaxf(smm[0].y, smm[1].y), fmaxf(smm[2].y, smm[3].y));
    const float mn_t = fminf(fminf(smm[0].z, smm[1].z), fminf(smm[2].z, smm[3].z));
    const float mx_t = fmaxf(fmaxf(smm[0].w, smm[1].w), fmaxf(smm[2].w, smm[3].w));

    const bool isRef = (lane < 32);
    const float mn = isRef ? mn_r : mn_t;
    const float sc = isRef ? (64.0f / (mx_r - mn_r)) : (64.0f / (mx_t - mn_t));
    const float* __restrict__ src = isRef ? ref : tar;
    unsigned short* T = wbase + (isRef ? 0 : TSIZE);
    const int col = lane & 31;

    const int img = blockIdx.x / SUBS;
    const int sub = blockIdx.x % SUBS;
    const int pbase = img * NPIX + sub * PPB + wave * PPW + col;

    f32x4 acc[4][4];
    #pragma unroll
    for (int a = 0; a < 4; ++a)
        #pragma unroll
        for (int b = 0; b < 4; ++b)
            acc[a][b] = (f32x4){0.f, 0.f, 0.f, 0.f};

    const unsigned short* aT = wbase;
    const unsigned short* bT = wbase + TSIZE;
    const int frow = (lane & 15) + 1;   // bin m -> physical row m+1
    const int fk = (lane >> 4) * 8;     // k slice within K=32

    int prev = 0;
    float vcur = src[pbase];
    for (int s = 0; s < STEPS; ++s) {
        float vnext = (s + 1 < STEPS) ? src[pbase + (s + 1) * 32] : 0.0f;
        float x = (vcur - mn) * sc;              // in [0, 64]
        float fx = floorf(x);
        int ib = (int)fx;                        // physical first row (= ir+1), 0..64
        float u = x - fx;
        float um = 1.0f - u;
        float w0 = um * um * um * (1.0f / 6.0f);
        float w1 = (2.0f / 3.0f) - u * u + 0.5f * u * u * u;
        float w2 = (2.0f / 3.0f) - um * um + 0.5f * um * um * um;
        float w3 = u * u * u * (1.0f / 6.0f);
        unsigned short h0 = f2bf(w0), h1 = f2bf(w1), h2 = f2bf(w2), h3 = f2bf(w3);

        // un-zero previous step's 4 cells, then scatter the new 4 (DS in-order per wave)
        unsigned short* tp = T + prev * TCOLS + col;
        tp[0] = 0; tp[TCOLS] = 0; tp[2 * TCOLS] = 0; tp[3 * TCOLS] = 0;
        unsigned short* tn = T + ib * TCOLS + col;
        tn[0] = h0; tn[TCOLS] = h1; tn[2 * TCOLS] = h2; tn[3 * TCOLS] = h3;
        prev = ib;

        bf16x8 af[4], bfr[4];
        #pragma unroll
        for (int mt = 0; mt < 4; ++mt)
            af[mt] = *(const bf16x8*)(aT + (mt * 16 + frow) * TCOLS + fk);
        #pragma unroll
        for (int nt = 0; nt < 4; ++nt)
            bfr[nt] = *(const bf16x8*)(bT + (nt * 16 + frow) * TCOLS + fk);
        #pragma unroll
        for (int mt = 0; mt < 4; ++mt)
            #pragma unroll
            for (int nt = 0; nt < 4; ++nt)
                acc[mt][nt] = __builtin_amdgcn_mfma_f32_16x16x32_bf16(
                    af[mt], bfr[nt], acc[mt][nt], 0, 0, 0);
        vcur = vnext;
    }

    // ---- combine the 4 waves' C into cbuf (C/D: col=lane&15, row=quad*4+reg) ----
    const int crow0 = (lane >> 4) * 4;
    const int ccol = lane & 15;
    for (int ph = 0; ph < 4; ++ph) {
        if (wave == ph) {
            #pragma unroll
            for (int mt = 0; mt < 4; ++mt)
                #pragma unroll
                for (int nt = 0; nt < 4; ++nt)
                    #pragma unroll
                    for (int r = 0; r < 4; ++r) {
                        int idx = (mt * 16 + crow0 + r) * 65 + nt * 16 + ccol;
                        if (ph == 0) cbuf[idx] = acc[mt][nt][r];
                        else cbuf[idx] += acc[mt][nt][r];
                    }
        }
        __syncthreads();
    }
    // fused epilogue: accumulate block partial into out (zeroed by memset node)
    float* po = out + img * HIST_SIZE;
    for (int c = tid; c < HIST_SIZE; c += H_THREADS)
        atomicAdd(&po[c], cbuf[(c >> 6) * 65 + (c & 63)] * 4096.0f);  // 1/EPS^2
}

extern "C" void kernel_launch(void* const* d_in, const int* in_sizes, int n_in,
                              void* d_out, int out_size, void* d_ws, size_t ws_size,
                              hipStream_t stream) {
    const float* ref = (const float*)d_in[0];
    const float* tar = (const float*)d_in[1];
    float* out = (float*)d_out;

    float4* mmpart = (float4*)d_ws;

    // out is re-poisoned to 0xAA before every replay: zero it (memset node is
    // graph-capture-safe; float 0.0f == all-zero bytes).
    hipMemsetAsync(out, 0, (size_t)out_size * sizeof(float), stream);
    minmax_part<<<MM_BLOCKS, MM_THREADS, 0, stream>>>(
        (const float4*)ref, (const float4*)tar, mmpart);
    hist_gemm<<<H_BLOCKS, H_THREADS, 0, stream>>>(ref, tar, mmpart, out);
}